// Round 10
// baseline (482.437 us; speedup 1.0000x reference)
//
#include <hip/hip_runtime.h>
#include <hip/hip_fp16.h>
#include <math.h>

#define HEADS 4
#define OUT_F 32
#define HF 128      // HEADS*OUT_F
#define IN_F 64
#define EDGE_F 16

typedef int   v4i __attribute__((ext_vector_type(4)));
typedef float v4f __attribute__((ext_vector_type(4)));
typedef float v2f __attribute__((ext_vector_type(2)));

// ---------- R13: chain structure, push folded into edge kernel + 4-way chains ----------
// R12 measured: gather 167us (serial 1-chain chase, latency-bound: occ 71%, VALU 23%,
// 1.6TB/s effective) and node_chain ~150us (atomicExch + DEPENDENT next[e] store = full
// round-trip per edge, unlike R0's fire-and-forget atomicAdd hist).
// Fixes:
//  (1) edge_logits does the push itself: old = atomicExch(head,e) RETURNS the next
//      pointer -> goes straight into pay[e].w. Chain-push phase + next[] deleted;
//      atomic latency hides under ea streaming (R5 early-atomic pattern).
//  (2) 4 chains per dst (head[dst*4+(e&3)]): gather walks 4 independent chains
//      concurrently -> 4 dependent-load chains in flight -> latency exposure /4.
// Dispatches: memset(head) + k_project + k_edge_logits + k_gather.

// ---------- projection: exact R0 loop, 32 nodes/block ----------
__global__ __launch_bounds__(128) void k_project(
    const float* __restrict__ x, const float* __restrict__ W_lin,
    const float* __restrict__ W_res, const float* __restrict__ bias,
    const float* __restrict__ w_s, const float* __restrict__ w_t,
    const float* __restrict__ b_s, const float* __restrict__ b_t,
    __half* __restrict__ xp, float* __restrict__ a_s, float* __restrict__ a_t,
    float* __restrict__ out, int N_) {
  __shared__ float4 sx[8][16];
  int c = threadIdx.x;  // output feature 0..127
  float4 wl[16], wr[16];
  const float4* Wl4 = (const float4*)(W_lin + c * IN_F);
  const float4* Wr4 = (const float4*)(W_res + c * IN_F);
#pragma unroll
  for (int k = 0; k < 16; k++) { wl[k] = Wl4[k]; wr[k] = Wr4[k]; }
  float wsl = w_s[c & 31], wtl = w_t[c & 31];
  float bsv = b_s[0], btv = b_t[0], bv = bias[c];
  int nstart = blockIdx.x * 32;
  for (int tile = 0; tile < 4; tile++) {
    int tbase = nstart + tile * 8;
    {
      int r = c >> 4, q = c & 15;
      int nn = tbase + r;
      sx[r][q] = (nn < N_) ? ((const float4*)(x + (size_t)nn * IN_F))[q]
                           : make_float4(0.f, 0.f, 0.f, 0.f);
    }
    __syncthreads();
    for (int ni = 0; ni < 8; ni++) {
      int n = tbase + ni;
      if (n >= N_) break;  // uniform across block
      float acc = 0.f, accr = 0.f;
#pragma unroll
      for (int k = 0; k < 16; k++) {
        float4 xv = sx[ni][k];
        acc  += xv.x * wl[k].x + xv.y * wl[k].y + xv.z * wl[k].z + xv.w * wl[k].w;
        accr += xv.x * wr[k].x + xv.y * wr[k].y + xv.z * wr[k].z + xv.w * wr[k].w;
      }
      xp[(size_t)n * HF + c] = __float2half(acc);
      out[(size_t)n * HF + c] = accr + bv;
      float vs = acc * wsl, vt = acc * wtl;
#pragma unroll
      for (int d = 16; d > 0; d >>= 1) {
        vs += __shfl_down(vs, d, 32);
        vt += __shfl_down(vt, d, 32);
      }
      if ((c & 31) == 0) {
        a_s[n * 4 + (c >> 5)] = vs + bsv;
        a_t[n * 4 + (c >> 5)] = vt + btv;
      }
    }
    __syncthreads();
  }
}

// ---------- per-edge: logits + exp + chain push (atomicExch returns next) ----------
__global__ __launch_bounds__(256) void k_edge_logits(
    const int* __restrict__ ei, const float* __restrict__ ea,
    const float* __restrict__ W_edge, const float* __restrict__ w_e,
    const float* __restrict__ b_e,
    const float* __restrict__ a_s, const float* __restrict__ a_t,
    int* __restrict__ head, v4i* __restrict__ pay, int E_) {
  __shared__ float sv[64];
  {
    int t = threadIdx.x;
    if (t < 64) {  // fold W_edge (128x16) with w_e -> v_e[4][16], from L2
      int h = t >> 4, cc = t & 15;
      float se = 0.f;
#pragma unroll
      for (int f = 0; f < 32; f++) se += W_edge[(h * 32 + f) * 16 + cc] * w_e[f];
      sv[t] = se;
    }
  }
  __syncthreads();
  int e = blockIdx.x * 256 + threadIdx.x;
  if (e >= E_) return;
  int src = ei[e], dst = ei[E_ + e];
  // early atomic: old head IS the next pointer; consumed only by the final store,
  // so the round-trip hides under the streaming loads + logit math below.
  int nx = atomicExch(head + dst * 4 + (e & 3), e);
  float bev = b_e[0];
  const v4f* ea4 = (const v4f*)(ea + (size_t)e * EDGE_F);
  v4f e0 = __builtin_nontemporal_load(ea4 + 0);   // streamed: read-once
  v4f e1 = __builtin_nontemporal_load(ea4 + 1);
  v4f e2 = __builtin_nontemporal_load(ea4 + 2);
  v4f e3 = __builtin_nontemporal_load(ea4 + 3);
  float4 as4 = *(const float4*)(a_s + src * 4);   // random 16B, L2-resident (800KB)
  float4 at4 = *(const float4*)(a_t + dst * 4);
  float asv[4] = {as4.x, as4.y, as4.z, as4.w};
  float atv[4] = {at4.x, at4.y, at4.z, at4.w};
  float res[4];
#pragma unroll
  for (int h = 0; h < 4; h++) {
    const float* v = sv + h * 16;
    float ae =
        e0.x * v[0]  + e0.y * v[1]  + e0.z * v[2]  + e0.w * v[3]
      + e1.x * v[4]  + e1.y * v[5]  + e1.z * v[6]  + e1.w * v[7]
      + e2.x * v[8]  + e2.y * v[9]  + e2.z * v[10] + e2.w * v[11]
      + e3.x * v[12] + e3.y * v[13] + e3.z * v[14] + e3.w * v[15];
    float al = asv[h] + atv[h] + ae + bev;
    al = al >= 0.f ? al : 0.2f * al;
    res[h] = __expf(al);  // shift-free softmax: |alpha| is O(1)
  }
  __half2 h01 = __floats2half2_rn(res[0], res[1]);
  __half2 h23 = __floats2half2_rn(res[2], res[3]);
  v4i pk;
  pk.x = src;
  pk.y = *(int*)&h01;
  pk.z = *(int*)&h23;
  pk.w = nx;               // next pointer from the atomic -> 1 load/step in gather
  pay[e] = pk;             // COALESCED store
}

// ---------- gather: one wave per dst node, 4 concurrent chain walks ----------
__global__ __launch_bounds__(256) void k_gather(
    const int* __restrict__ head, const v4i* __restrict__ pay,
    const __half* __restrict__ xp, float* __restrict__ out, int N_, int E_) {
  int wid = threadIdx.x >> 6, lane = threadIdx.x & 63;
  int n = blockIdx.x * 4 + wid;
  if (n >= N_) return;
  int e0 = head[n * 4 + 0], e1 = head[n * 4 + 1];
  int e2 = head[n * 4 + 2], e3 = head[n * 4 + 3];
  if (e0 < 0 && e1 < 0 && e2 < 0 && e3 < 0) return;  // no in-edges: keep residual
  int h = lane >> 4;  // features 2*lane, 2*lane+1 -> head (2*lane)>>5 = lane>>4
  float2 acc = make_float2(0.f, 0.f);
  float se = 0.f;
#define CHAIN_STEP(P)                                                    \
  {                                                                      \
    unsigned hw = (h < 2) ? (unsigned)(P).y : (unsigned)(P).z;           \
    unsigned bits = (h & 1) ? (hw >> 16) : (hw & 0xffffu);               \
    float ev = __half2float(__ushort_as_half((unsigned short)bits));     \
    const __half2* xr = (const __half2*)(xp + (size_t)(P).x * HF);       \
    float2 xv = __half22float2(xr[lane]);                                \
    acc.x += ev * xv.x;                                                  \
    acc.y += ev * xv.y;                                                  \
    se += ev;                                                            \
  }
  for (int it = 0; it < E_; ++it) {  // cap: inert on correct data
    bool a0 = e0 >= 0, a1 = e1 >= 0, a2 = e2 >= 0, a3 = e3 >= 0;
    if (!(a0 | a1 | a2 | a3)) break;
    v4i p0, p1, p2, p3;
    // issue all chase loads first: 4 independent dependence chains in flight
    if (a0) p0 = pay[e0];
    if (a1) p1 = pay[e1];
    if (a2) p2 = pay[e2];
    if (a3) p3 = pay[e3];
    if (a0) { CHAIN_STEP(p0); e0 = p0.w; }
    if (a1) { CHAIN_STEP(p1); e1 = p1.w; }
    if (a2) { CHAIN_STEP(p2); e2 = p2.w; }
    if (a3) { CHAIN_STEP(p3); e3 = p3.w; }
  }
#undef CHAIN_STEP
  float r = 1.f / se;  // se > 0: at least one edge processed, expv > 0
  size_t oi = (size_t)n * 64 + lane;
  v2f o = __builtin_nontemporal_load((const v2f*)out + oi);
  o.x += acc.x * r;
  o.y += acc.y * r;
  __builtin_nontemporal_store(o, (v2f*)out + oi);
}

extern "C" void kernel_launch(void* const* d_in, const int* in_sizes, int n_in,
                              void* d_out, int out_size, void* d_ws, size_t ws_size,
                              hipStream_t stream) {
  const float* x      = (const float*)d_in[0];
  const int*   ei     = (const int*)  d_in[1];
  const float* ea     = (const float*)d_in[2];
  const float* W_lin  = (const float*)d_in[3];
  const float* w_s    = (const float*)d_in[4];
  const float* b_s    = (const float*)d_in[5];
  const float* w_t    = (const float*)d_in[6];
  const float* b_t    = (const float*)d_in[7];
  const float* W_edge = (const float*)d_in[8];
  const float* w_e    = (const float*)d_in[9];
  const float* b_e    = (const float*)d_in[10];
  const float* W_res  = (const float*)d_in[11];
  const float* bias   = (const float*)d_in[12];
  int N_ = in_sizes[0] / IN_F;
  int E_ = in_sizes[1] / 2;
  float* out = (float*)d_out;

  // ws layout (~40.1 MB):
  // xp[N*128] f16 | pay[E] int4 | a_s[N*4] f32 | a_t[N*4] f32 | head[N*4]
  __half* xp    = (__half*)d_ws;
  v4i*    pay   = (v4i*)(xp + (size_t)N_ * HF);
  float*  a_s   = (float*)(pay + E_);
  float*  a_t   = a_s + (size_t)N_ * 4;
  int*    head  = (int*)(a_t + (size_t)N_ * 4);

  int NB = (N_ + 31) / 32;  // projection blocks

  hipMemsetAsync(head, 0xFF, (size_t)N_ * 4 * sizeof(int), stream);  // head = -1
  k_project<<<NB, 128, 0, stream>>>(
      x, W_lin, W_res, bias, w_s, w_t, b_s, b_t, xp, a_s, a_t, out, N_);
  k_edge_logits<<<(E_ + 255) / 256, 256, 0, stream>>>(
      ei, ea, W_edge, w_e, b_e, a_s, a_t, head, pay, E_);
  k_gather<<<(N_ + 3) / 4, 256, 0, stream>>>(head, pay, xp, out, N_, E_);
}

// Round 11
// 434.921 us; speedup vs baseline: 1.1093x; 1.1093x over previous
//
#include <hip/hip_runtime.h>
#include <hip/hip_fp16.h>
#include <math.h>

#define HEADS 4
#define OUT_F 32
#define HF 128      // HEADS*OUT_F
#define IN_F 64
#define EDGE_F 16

typedef int   v4i __attribute__((ext_vector_type(4)));
typedef float v4f __attribute__((ext_vector_type(4)));
typedef float v2f __attribute__((ext_vector_type(2)));
typedef _Float16 v8h __attribute__((ext_vector_type(8)));

// ---------- R14: MFMA projection (chain structure otherwise unchanged from R13) ----------
// R13 measured: 4-way chains did NOT speed gather (173us, FETCH 267MB unchanged) ->
// gather is random-line-traffic-bound, not latency-bound; chain vs sorted is a wash
// (465 vs 482). The clean structure-independent win: projection is a dense GEMM on the
// VECTOR pipe (~100-114us measured in R9 split). Rewritten with mfma_f32_16x16x32_f16:
// W_lin||W_res staged f16 in LDS [256][72] (pad 8 -> 2-way-free banks), x-tile [64][72],
// 4 waves x 16-node M-tile x 16 N-tiles x 2 K = 32 MFMA/wave. a_s/a_t reduced from f32
// accumulators via 16-lane shfl_xor. f16 inputs + f32 accum: added err ~4e-4 << 0.0078.

__global__ __launch_bounds__(256) void k_project_mfma(
    const float* __restrict__ x, const float* __restrict__ W_lin,
    const float* __restrict__ W_res, const float* __restrict__ bias,
    const float* __restrict__ w_s, const float* __restrict__ w_t,
    const float* __restrict__ b_s, const float* __restrict__ b_t,
    __half* __restrict__ xp, float* __restrict__ a_s, float* __restrict__ a_t,
    float* __restrict__ out, int N_) {
  __shared__ __half sw[256][72];   // [outc 0..255][k 0..63], rows 0-127 = W_lin, 128-255 = W_res
  __shared__ __half sxh[64][72];   // [node][k]
  int t = threadIdx.x;
  // ---- stage weights (f32 -> f16) ----
  {
    const float* wsrc = (t < 128) ? (W_lin + t * IN_F) : (W_res + (size_t)(t - 128) * IN_F);
    const float4* w4 = (const float4*)wsrc;
#pragma unroll
    for (int k8 = 0; k8 < 8; k8++) {
      float4 f0 = w4[k8 * 2 + 0];
      float4 f1 = w4[k8 * 2 + 1];
      *(__half2*)(&sw[t][k8 * 8 + 0]) = __floats2half2_rn(f0.x, f0.y);
      *(__half2*)(&sw[t][k8 * 8 + 2]) = __floats2half2_rn(f0.z, f0.w);
      *(__half2*)(&sw[t][k8 * 8 + 4]) = __floats2half2_rn(f1.x, f1.y);
      *(__half2*)(&sw[t][k8 * 8 + 6]) = __floats2half2_rn(f1.z, f1.w);
    }
  }
  // ---- stage x tile (64 nodes, f32 -> f16) ----
  int n0 = blockIdx.x * 64;
  {
    int node = t >> 2, q = t & 3;        // 4 threads per node, 16 floats each
    int nn = n0 + node;
    const float4* xs = (const float4*)(x + (size_t)nn * IN_F) + q * 4;
#pragma unroll
    for (int j = 0; j < 4; j++) {
      float4 f = (nn < N_) ? xs[j] : make_float4(0.f, 0.f, 0.f, 0.f);
      int col = q * 16 + j * 4;
      *(__half2*)(&sxh[node][col + 0]) = __floats2half2_rn(f.x, f.y);
      *(__half2*)(&sxh[node][col + 2]) = __floats2half2_rn(f.z, f.w);
    }
  }
  __syncthreads();

  int w = t >> 6, l = t & 63;
  int lm = l & 15, lg = l >> 4;          // D: col=lm, row=lg*4+reg
  int mbase = n0 + w * 16;
  // A fragments for this wave's 16-node M-tile (row = lm, k = lg*8 + j)
  v8h a0 = *(const v8h*)(&sxh[w * 16 + lm][lg * 8]);
  v8h a1 = *(const v8h*)(&sxh[w * 16 + lm][32 + lg * 8]);

  float ws_lo = w_s[lm], ws_hi = w_s[16 + lm];
  float wt_lo = w_t[lm], wt_hi = w_t[16 + lm];
  float bsv = b_s[0], btv = b_t[0];

  float sacc[4] = {0.f, 0.f, 0.f, 0.f};
  float tacc[4] = {0.f, 0.f, 0.f, 0.f};

#pragma unroll
  for (int nt = 0; nt < 16; nt++) {
    // B fragment: col = nt*16+lm (row of sw), k = kb*32 + lg*8
    v8h b0 = *(const v8h*)(&sw[nt * 16 + lm][lg * 8]);
    v8h b1 = *(const v8h*)(&sw[nt * 16 + lm][32 + lg * 8]);
    v4f d = {0.f, 0.f, 0.f, 0.f};
    d = __builtin_amdgcn_mfma_f32_16x16x32_f16(a0, b0, d, 0, 0, 0);
    d = __builtin_amdgcn_mfma_f32_16x16x32_f16(a1, b1, d, 0, 0, 0);
    if (nt < 8) {
      // lin features c = nt*16+lm -> xp f16 + attention partials
      int c = nt * 16 + lm;
      float wssel = (nt & 1) ? ws_hi : ws_lo;
      float wtsel = (nt & 1) ? wt_hi : wt_lo;
#pragma unroll
      for (int reg = 0; reg < 4; reg++) {
        int m = mbase + lg * 4 + reg;
        if (m < N_) xp[(size_t)m * HF + c] = __float2half(d[reg]);
        sacc[reg] += d[reg] * wssel;
        tacc[reg] += d[reg] * wtsel;
      }
      if (nt & 1) {  // head h = nt>>1 complete: reduce over the 16-lane c-group
        int h = nt >> 1;
#pragma unroll
        for (int reg = 0; reg < 4; reg++) {
#pragma unroll
          for (int dlt = 8; dlt > 0; dlt >>= 1) {
            sacc[reg] += __shfl_xor(sacc[reg], dlt, 64);
            tacc[reg] += __shfl_xor(tacc[reg], dlt, 64);
          }
        }
        if (lm == 0) {
#pragma unroll
          for (int reg = 0; reg < 4; reg++) {
            int m = mbase + lg * 4 + reg;
            if (m < N_) {
              a_s[m * 4 + h] = sacc[reg] + bsv;
              a_t[m * 4 + h] = tacc[reg] + btv;
            }
          }
        }
#pragma unroll
        for (int reg = 0; reg < 4; reg++) { sacc[reg] = 0.f; tacc[reg] = 0.f; }
      }
    } else {
      // res features c = (nt-8)*16+lm -> out f32 + bias
      int c = (nt - 8) * 16 + lm;
      float bv = bias[c];
#pragma unroll
      for (int reg = 0; reg < 4; reg++) {
        int m = mbase + lg * 4 + reg;
        if (m < N_) out[(size_t)m * HF + c] = d[reg] + bv;
      }
    }
  }
}

// ---------- per-edge: logits + exp + chain push (atomicExch returns next) ----------
__global__ __launch_bounds__(256) void k_edge_logits(
    const int* __restrict__ ei, const float* __restrict__ ea,
    const float* __restrict__ W_edge, const float* __restrict__ w_e,
    const float* __restrict__ b_e,
    const float* __restrict__ a_s, const float* __restrict__ a_t,
    int* __restrict__ head, v4i* __restrict__ pay, int E_) {
  __shared__ float sv[64];
  {
    int t = threadIdx.x;
    if (t < 64) {  // fold W_edge (128x16) with w_e -> v_e[4][16], from L2
      int h = t >> 4, cc = t & 15;
      float se = 0.f;
#pragma unroll
      for (int f = 0; f < 32; f++) se += W_edge[(h * 32 + f) * 16 + cc] * w_e[f];
      sv[t] = se;
    }
  }
  __syncthreads();
  int e = blockIdx.x * 256 + threadIdx.x;
  if (e >= E_) return;
  int src = ei[e], dst = ei[E_ + e];
  // early atomic: old head IS the next pointer; consumed only by the final store,
  // so the round-trip hides under the streaming loads + logit math below.
  int nx = atomicExch(head + dst * 4 + (e & 3), e);
  float bev = b_e[0];
  const v4f* ea4 = (const v4f*)(ea + (size_t)e * EDGE_F);
  v4f e0 = __builtin_nontemporal_load(ea4 + 0);   // streamed: read-once
  v4f e1 = __builtin_nontemporal_load(ea4 + 1);
  v4f e2 = __builtin_nontemporal_load(ea4 + 2);
  v4f e3 = __builtin_nontemporal_load(ea4 + 3);
  float4 as4 = *(const float4*)(a_s + src * 4);   // random 16B, L2-resident (800KB)
  float4 at4 = *(const float4*)(a_t + dst * 4);
  float asv[4] = {as4.x, as4.y, as4.z, as4.w};
  float atv[4] = {at4.x, at4.y, at4.z, at4.w};
  float res[4];
#pragma unroll
  for (int h = 0; h < 4; h++) {
    const float* v = sv + h * 16;
    float ae =
        e0.x * v[0]  + e0.y * v[1]  + e0.z * v[2]  + e0.w * v[3]
      + e1.x * v[4]  + e1.y * v[5]  + e1.z * v[6]  + e1.w * v[7]
      + e2.x * v[8]  + e2.y * v[9]  + e2.z * v[10] + e2.w * v[11]
      + e3.x * v[12] + e3.y * v[13] + e3.z * v[14] + e3.w * v[15];
    float al = asv[h] + atv[h] + ae + bev;
    al = al >= 0.f ? al : 0.2f * al;
    res[h] = __expf(al);  // shift-free softmax: |alpha| is O(1)
  }
  __half2 h01 = __floats2half2_rn(res[0], res[1]);
  __half2 h23 = __floats2half2_rn(res[2], res[3]);
  v4i pk;
  pk.x = src;
  pk.y = *(int*)&h01;
  pk.z = *(int*)&h23;
  pk.w = nx;               // next pointer from the atomic -> 1 load/step in gather
  pay[e] = pk;             // COALESCED store
}

// ---------- gather: one wave per dst node, 4 concurrent chain walks ----------
__global__ __launch_bounds__(256) void k_gather(
    const int* __restrict__ head, const v4i* __restrict__ pay,
    const __half* __restrict__ xp, float* __restrict__ out, int N_, int E_) {
  int wid = threadIdx.x >> 6, lane = threadIdx.x & 63;
  int n = blockIdx.x * 4 + wid;
  if (n >= N_) return;
  int e0 = head[n * 4 + 0], e1 = head[n * 4 + 1];
  int e2 = head[n * 4 + 2], e3 = head[n * 4 + 3];
  if (e0 < 0 && e1 < 0 && e2 < 0 && e3 < 0) return;  // no in-edges: keep residual
  int h = lane >> 4;  // features 2*lane, 2*lane+1 -> head (2*lane)>>5 = lane>>4
  float2 acc = make_float2(0.f, 0.f);
  float se = 0.f;
#define CHAIN_STEP(P)                                                    \
  {                                                                      \
    unsigned hw = (h < 2) ? (unsigned)(P).y : (unsigned)(P).z;           \
    unsigned bits = (h & 1) ? (hw >> 16) : (hw & 0xffffu);               \
    float ev = __half2float(__ushort_as_half((unsigned short)bits));     \
    const __half2* xr = (const __half2*)(xp + (size_t)(P).x * HF);       \
    float2 xv = __half22float2(xr[lane]);                                \
    acc.x += ev * xv.x;                                                  \
    acc.y += ev * xv.y;                                                  \
    se += ev;                                                            \
  }
  for (int it = 0; it < E_; ++it) {  // cap: inert on correct data
    bool a0 = e0 >= 0, a1 = e1 >= 0, a2 = e2 >= 0, a3 = e3 >= 0;
    if (!(a0 | a1 | a2 | a3)) break;
    v4i p0, p1, p2, p3;
    // issue all chase loads first: 4 independent dependence chains in flight
    if (a0) p0 = pay[e0];
    if (a1) p1 = pay[e1];
    if (a2) p2 = pay[e2];
    if (a3) p3 = pay[e3];
    if (a0) { CHAIN_STEP(p0); e0 = p0.w; }
    if (a1) { CHAIN_STEP(p1); e1 = p1.w; }
    if (a2) { CHAIN_STEP(p2); e2 = p2.w; }
    if (a3) { CHAIN_STEP(p3); e3 = p3.w; }
  }
#undef CHAIN_STEP
  float r = 1.f / se;  // se > 0: at least one edge processed, expv > 0
  size_t oi = (size_t)n * 64 + lane;
  v2f o = __builtin_nontemporal_load((const v2f*)out + oi);
  o.x += acc.x * r;
  o.y += acc.y * r;
  __builtin_nontemporal_store(o, (v2f*)out + oi);
}

extern "C" void kernel_launch(void* const* d_in, const int* in_sizes, int n_in,
                              void* d_out, int out_size, void* d_ws, size_t ws_size,
                              hipStream_t stream) {
  const float* x      = (const float*)d_in[0];
  const int*   ei     = (const int*)  d_in[1];
  const float* ea     = (const float*)d_in[2];
  const float* W_lin  = (const float*)d_in[3];
  const float* w_s    = (const float*)d_in[4];
  const float* b_s    = (const float*)d_in[5];
  const float* w_t    = (const float*)d_in[6];
  const float* b_t    = (const float*)d_in[7];
  const float* W_edge = (const float*)d_in[8];
  const float* w_e    = (const float*)d_in[9];
  const float* b_e    = (const float*)d_in[10];
  const float* W_res  = (const float*)d_in[11];
  const float* bias   = (const float*)d_in[12];
  int N_ = in_sizes[0] / IN_F;
  int E_ = in_sizes[1] / 2;
  float* out = (float*)d_out;

  // ws layout (~40.1 MB):
  // xp[N*128] f16 | pay[E] int4 | a_s[N*4] f32 | a_t[N*4] f32 | head[N*4]
  __half* xp    = (__half*)d_ws;
  v4i*    pay   = (v4i*)(xp + (size_t)N_ * HF);
  float*  a_s   = (float*)(pay + E_);
  float*  a_t   = a_s + (size_t)N_ * 4;
  int*    head  = (int*)(a_t + (size_t)N_ * 4);

  int PB = (N_ + 63) / 64;  // projection blocks (64 nodes each)

  hipMemsetAsync(head, 0xFF, (size_t)N_ * 4 * sizeof(int), stream);  // head = -1
  k_project_mfma<<<PB, 256, 0, stream>>>(
      x, W_lin, W_res, bias, w_s, w_t, b_s, b_t, xp, a_s, a_t, out, N_);
  k_edge_logits<<<(E_ + 255) / 256, 256, 0, stream>>>(
      ei, ea, W_edge, w_e, b_e, a_s, a_t, head, pay, E_);
  k_gather<<<(N_ + 3) / 4, 256, 0, stream>>>(head, pay, xp, out, N_, E_);
}

// Round 12
// 362.063 us; speedup vs baseline: 1.3325x; 1.2012x over previous
//
#include <hip/hip_runtime.h>
#include <hip/hip_fp16.h>
#include <math.h>

#define HEADS 4
#define OUT_F 32
#define HF 128      // HEADS*OUT_F
#define IN_F 64
#define EDGE_F 16

typedef int   v4i __attribute__((ext_vector_type(4)));
typedef float v4f __attribute__((ext_vector_type(4)));
typedef float v2f __attribute__((ext_vector_type(2)));
typedef _Float16 v8h __attribute__((ext_vector_type(8)));

// ---------- R15: branch-free 4-chain gather + memset folded into projection ----------
// R14 measured: gather pinned at 173us across 1-chain and 4-chain variants, VGPR=20.
// 20 VGPRs cannot hold 4 live v4i payloads -> the if-guarded chase loads were compiled
// into separate BBs and SERIALIZED; the "4-way" experiment never ran 4-wide. The serial
// model (32 edges x ~1200cyc x 50000 tasks / ~5900 waves ~ 136-170us) matches measurement.
// Fix: predicated straight-line chase -- dead cursors clamp to 0, all 4 pay loads issued
// unconditionally, then all 4 xp row loads, then FMAs; dead chains multiply by 0.
// Also: head-init blocks appended to the projection grid (drops the memset dispatch).

__global__ __launch_bounds__(256) void k_project_mfma(
    const float* __restrict__ x, const float* __restrict__ W_lin,
    const float* __restrict__ W_res, const float* __restrict__ bias,
    const float* __restrict__ w_s, const float* __restrict__ w_t,
    const float* __restrict__ b_s, const float* __restrict__ b_t,
    __half* __restrict__ xp, float* __restrict__ a_s, float* __restrict__ a_t,
    float* __restrict__ out, int* __restrict__ head, int N_, int PB) {
  if (blockIdx.x >= PB) {  // head-init block (was hipMemsetAsync)
    int i = (blockIdx.x - PB) * 256 + threadIdx.x;
    if (i < N_ * 4) head[i] = -1;
    return;
  }
  __shared__ __half sw[256][72];   // [outc 0..255][k], rows 0-127 = W_lin, 128-255 = W_res
  __shared__ __half sxh[64][72];   // [node][k]
  int t = threadIdx.x;
  // ---- stage weights (f32 -> f16) ----
  {
    const float* wsrc = (t < 128) ? (W_lin + t * IN_F) : (W_res + (size_t)(t - 128) * IN_F);
    const float4* w4 = (const float4*)wsrc;
#pragma unroll
    for (int k8 = 0; k8 < 8; k8++) {
      float4 f0 = w4[k8 * 2 + 0];
      float4 f1 = w4[k8 * 2 + 1];
      *(__half2*)(&sw[t][k8 * 8 + 0]) = __floats2half2_rn(f0.x, f0.y);
      *(__half2*)(&sw[t][k8 * 8 + 2]) = __floats2half2_rn(f0.z, f0.w);
      *(__half2*)(&sw[t][k8 * 8 + 4]) = __floats2half2_rn(f1.x, f1.y);
      *(__half2*)(&sw[t][k8 * 8 + 6]) = __floats2half2_rn(f1.z, f1.w);
    }
  }
  // ---- stage x tile (64 nodes, f32 -> f16) ----
  int n0 = blockIdx.x * 64;
  {
    int node = t >> 2, q = t & 3;        // 4 threads per node, 16 floats each
    int nn = n0 + node;
    const float4* xs = (const float4*)(x + (size_t)nn * IN_F) + q * 4;
#pragma unroll
    for (int j = 0; j < 4; j++) {
      float4 f = (nn < N_) ? xs[j] : make_float4(0.f, 0.f, 0.f, 0.f);
      int col = q * 16 + j * 4;
      *(__half2*)(&sxh[node][col + 0]) = __floats2half2_rn(f.x, f.y);
      *(__half2*)(&sxh[node][col + 2]) = __floats2half2_rn(f.z, f.w);
    }
  }
  __syncthreads();

  int w = t >> 6, l = t & 63;
  int lm = l & 15, lg = l >> 4;          // D: col=lm, row=lg*4+reg
  int mbase = n0 + w * 16;
  // A fragments for this wave's 16-node M-tile (row = lm, k = lg*8 + j)
  v8h a0 = *(const v8h*)(&sxh[w * 16 + lm][lg * 8]);
  v8h a1 = *(const v8h*)(&sxh[w * 16 + lm][32 + lg * 8]);

  float ws_lo = w_s[lm], ws_hi = w_s[16 + lm];
  float wt_lo = w_t[lm], wt_hi = w_t[16 + lm];
  float bsv = b_s[0], btv = b_t[0];

  float sacc[4] = {0.f, 0.f, 0.f, 0.f};
  float tacc[4] = {0.f, 0.f, 0.f, 0.f};

#pragma unroll
  for (int nt = 0; nt < 16; nt++) {
    // B fragment: col = nt*16+lm (row of sw), k = kb*32 + lg*8
    v8h b0 = *(const v8h*)(&sw[nt * 16 + lm][lg * 8]);
    v8h b1 = *(const v8h*)(&sw[nt * 16 + lm][32 + lg * 8]);
    v4f d = {0.f, 0.f, 0.f, 0.f};
    d = __builtin_amdgcn_mfma_f32_16x16x32_f16(a0, b0, d, 0, 0, 0);
    d = __builtin_amdgcn_mfma_f32_16x16x32_f16(a1, b1, d, 0, 0, 0);
    if (nt < 8) {
      // lin features c = nt*16+lm -> xp f16 + attention partials
      int c = nt * 16 + lm;
      float wssel = (nt & 1) ? ws_hi : ws_lo;
      float wtsel = (nt & 1) ? wt_hi : wt_lo;
#pragma unroll
      for (int reg = 0; reg < 4; reg++) {
        int m = mbase + lg * 4 + reg;
        if (m < N_) xp[(size_t)m * HF + c] = __float2half(d[reg]);
        sacc[reg] += d[reg] * wssel;
        tacc[reg] += d[reg] * wtsel;
      }
      if (nt & 1) {  // head h = nt>>1 complete: reduce over the 16-lane c-group
        int h = nt >> 1;
#pragma unroll
        for (int reg = 0; reg < 4; reg++) {
#pragma unroll
          for (int dlt = 8; dlt > 0; dlt >>= 1) {
            sacc[reg] += __shfl_xor(sacc[reg], dlt, 64);
            tacc[reg] += __shfl_xor(tacc[reg], dlt, 64);
          }
        }
        if (lm == 0) {
#pragma unroll
          for (int reg = 0; reg < 4; reg++) {
            int m = mbase + lg * 4 + reg;
            if (m < N_) {
              a_s[m * 4 + h] = sacc[reg] + bsv;
              a_t[m * 4 + h] = tacc[reg] + btv;
            }
          }
        }
#pragma unroll
        for (int reg = 0; reg < 4; reg++) { sacc[reg] = 0.f; tacc[reg] = 0.f; }
      }
    } else {
      // res features c = (nt-8)*16+lm -> out f32 + bias
      int c = (nt - 8) * 16 + lm;
      float bv = bias[c];
#pragma unroll
      for (int reg = 0; reg < 4; reg++) {
        int m = mbase + lg * 4 + reg;
        if (m < N_) out[(size_t)m * HF + c] = d[reg] + bv;
      }
    }
  }
}

// ---------- per-edge: logits + exp + chain push (atomicExch returns next) ----------
__global__ __launch_bounds__(256) void k_edge_logits(
    const int* __restrict__ ei, const float* __restrict__ ea,
    const float* __restrict__ W_edge, const float* __restrict__ w_e,
    const float* __restrict__ b_e,
    const float* __restrict__ a_s, const float* __restrict__ a_t,
    int* __restrict__ head, v4i* __restrict__ pay, int E_) {
  __shared__ float sv[64];
  {
    int t = threadIdx.x;
    if (t < 64) {  // fold W_edge (128x16) with w_e -> v_e[4][16], from L2
      int h = t >> 4, cc = t & 15;
      float se = 0.f;
#pragma unroll
      for (int f = 0; f < 32; f++) se += W_edge[(h * 32 + f) * 16 + cc] * w_e[f];
      sv[t] = se;
    }
  }
  __syncthreads();
  int e = blockIdx.x * 256 + threadIdx.x;
  if (e >= E_) return;
  int src = ei[e], dst = ei[E_ + e];
  // early atomic: old head IS the next pointer; consumed only by the final store,
  // so the round-trip hides under the streaming loads + logit math below.
  int nx = atomicExch(head + dst * 4 + (e & 3), e);
  float bev = b_e[0];
  const v4f* ea4 = (const v4f*)(ea + (size_t)e * EDGE_F);
  v4f e0 = __builtin_nontemporal_load(ea4 + 0);   // streamed: read-once
  v4f e1 = __builtin_nontemporal_load(ea4 + 1);
  v4f e2 = __builtin_nontemporal_load(ea4 + 2);
  v4f e3 = __builtin_nontemporal_load(ea4 + 3);
  float4 as4 = *(const float4*)(a_s + src * 4);   // random 16B, L2-resident (800KB)
  float4 at4 = *(const float4*)(a_t + dst * 4);
  float asv[4] = {as4.x, as4.y, as4.z, as4.w};
  float atv[4] = {at4.x, at4.y, at4.z, at4.w};
  float res[4];
#pragma unroll
  for (int h = 0; h < 4; h++) {
    const float* v = sv + h * 16;
    float ae =
        e0.x * v[0]  + e0.y * v[1]  + e0.z * v[2]  + e0.w * v[3]
      + e1.x * v[4]  + e1.y * v[5]  + e1.z * v[6]  + e1.w * v[7]
      + e2.x * v[8]  + e2.y * v[9]  + e2.z * v[10] + e2.w * v[11]
      + e3.x * v[12] + e3.y * v[13] + e3.z * v[14] + e3.w * v[15];
    float al = asv[h] + atv[h] + ae + bev;
    al = al >= 0.f ? al : 0.2f * al;
    res[h] = __expf(al);  // shift-free softmax: |alpha| is O(1)
  }
  __half2 h01 = __floats2half2_rn(res[0], res[1]);
  __half2 h23 = __floats2half2_rn(res[2], res[3]);
  v4i pk;
  pk.x = src;
  pk.y = *(int*)&h01;
  pk.z = *(int*)&h23;
  pk.w = nx;               // next pointer from the atomic -> 1 load/step in gather
  pay[e] = pk;             // COALESCED store
}

// ---------- gather: one wave per dst, 4 chains, branch-free predicated chase ----------
__global__ __launch_bounds__(256) void k_gather(
    const int* __restrict__ head, const v4i* __restrict__ pay,
    const __half* __restrict__ xp, float* __restrict__ out, int N_, int E_) {
  int wid = threadIdx.x >> 6, lane = threadIdx.x & 63;
  int n = blockIdx.x * 4 + wid;
  if (n >= N_) return;
  int e0 = head[n * 4 + 0], e1 = head[n * 4 + 1];
  int e2 = head[n * 4 + 2], e3 = head[n * 4 + 3];
  if (e0 < 0 && e1 < 0 && e2 < 0 && e3 < 0) return;  // no in-edges: keep residual
  int h = lane >> 4;  // features 2*lane, 2*lane+1 -> head (2*lane)>>5 = lane>>4
  float2 acc = make_float2(0.f, 0.f);
  float se = 0.f;
  for (int it = 0; it < E_; ++it) {  // cap: inert on correct data
    if (e0 < 0 && e1 < 0 && e2 < 0 && e3 < 0) break;  // wave-uniform
    // clamp dead cursors to 0: loads become unconditional straight-line code
    int s0 = e0 < 0 ? 0 : e0, s1 = e1 < 0 ? 0 : e1;
    int s2 = e2 < 0 ? 0 : e2, s3 = e3 < 0 ? 0 : e3;
    v4i p0 = pay[s0];
    v4i p1 = pay[s1];
    v4i p2 = pay[s2];
    v4i p3 = pay[s3];
    float m0 = e0 < 0 ? 0.f : 1.f, m1 = e1 < 0 ? 0.f : 1.f;
    float m2 = e2 < 0 ? 0.f : 1.f, m3 = e3 < 0 ? 0.f : 1.f;
    unsigned hw0 = (h < 2) ? (unsigned)p0.y : (unsigned)p0.z;
    unsigned hw1 = (h < 2) ? (unsigned)p1.y : (unsigned)p1.z;
    unsigned hw2 = (h < 2) ? (unsigned)p2.y : (unsigned)p2.z;
    unsigned hw3 = (h < 2) ? (unsigned)p3.y : (unsigned)p3.z;
    unsigned b0 = (h & 1) ? (hw0 >> 16) : (hw0 & 0xffffu);
    unsigned b1 = (h & 1) ? (hw1 >> 16) : (hw1 & 0xffffu);
    unsigned b2 = (h & 1) ? (hw2 >> 16) : (hw2 & 0xffffu);
    unsigned b3 = (h & 1) ? (hw3 >> 16) : (hw3 & 0xffffu);
    float ev0 = m0 * __half2float(__ushort_as_half((unsigned short)b0));
    float ev1 = m1 * __half2float(__ushort_as_half((unsigned short)b1));
    float ev2 = m2 * __half2float(__ushort_as_half((unsigned short)b2));
    float ev3 = m3 * __half2float(__ushort_as_half((unsigned short)b3));
    // 4 independent row loads in flight together
    const __half2* x0 = (const __half2*)(xp + (size_t)p0.x * HF);
    const __half2* x1 = (const __half2*)(xp + (size_t)p1.x * HF);
    const __half2* x2 = (const __half2*)(xp + (size_t)p2.x * HF);
    const __half2* x3 = (const __half2*)(xp + (size_t)p3.x * HF);
    float2 v0 = __half22float2(x0[lane]);
    float2 v1 = __half22float2(x1[lane]);
    float2 v2 = __half22float2(x2[lane]);
    float2 v3 = __half22float2(x3[lane]);
    acc.x += ev0 * v0.x + ev1 * v1.x + ev2 * v2.x + ev3 * v3.x;
    acc.y += ev0 * v0.y + ev1 * v1.y + ev2 * v2.y + ev3 * v3.y;
    se += ev0 + ev1 + ev2 + ev3;
    e0 = e0 < 0 ? e0 : p0.w;
    e1 = e1 < 0 ? e1 : p1.w;
    e2 = e2 < 0 ? e2 : p2.w;
    e3 = e3 < 0 ? e3 : p3.w;
  }
  float r = 1.f / se;  // se > 0: at least one edge processed, expv > 0
  size_t oi = (size_t)n * 64 + lane;
  v2f o = __builtin_nontemporal_load((const v2f*)out + oi);
  o.x += acc.x * r;
  o.y += acc.y * r;
  __builtin_nontemporal_store(o, (v2f*)out + oi);
}

extern "C" void kernel_launch(void* const* d_in, const int* in_sizes, int n_in,
                              void* d_out, int out_size, void* d_ws, size_t ws_size,
                              hipStream_t stream) {
  const float* x      = (const float*)d_in[0];
  const int*   ei     = (const int*)  d_in[1];
  const float* ea     = (const float*)d_in[2];
  const float* W_lin  = (const float*)d_in[3];
  const float* w_s    = (const float*)d_in[4];
  const float* b_s    = (const float*)d_in[5];
  const float* w_t    = (const float*)d_in[6];
  const float* b_t    = (const float*)d_in[7];
  const float* W_edge = (const float*)d_in[8];
  const float* w_e    = (const float*)d_in[9];
  const float* b_e    = (const float*)d_in[10];
  const float* W_res  = (const float*)d_in[11];
  const float* bias   = (const float*)d_in[12];
  int N_ = in_sizes[0] / IN_F;
  int E_ = in_sizes[1] / 2;
  float* out = (float*)d_out;

  // ws layout (~40.1 MB):
  // xp[N*128] f16 | pay[E] int4 | a_s[N*4] f32 | a_t[N*4] f32 | head[N*4]
  __half* xp    = (__half*)d_ws;
  v4i*    pay   = (v4i*)(xp + (size_t)N_ * HF);
  float*  a_s   = (float*)(pay + E_);
  float*  a_t   = a_s + (size_t)N_ * 4;
  int*    head  = (int*)(a_t + (size_t)N_ * 4);

  int PB = (N_ + 63) / 64;               // projection blocks (64 nodes each)
  int HB = (N_ * 4 + 255) / 256;         // head-init blocks

  k_project_mfma<<<PB + HB, 256, 0, stream>>>(
      x, W_lin, W_res, bias, w_s, w_t, b_s, b_t, xp, a_s, a_t, out, head, N_, PB);
  k_edge_logits<<<(E_ + 255) / 256, 256, 0, stream>>>(
      ei, ea, W_edge, w_e, b_e, a_s, a_t, head, pay, E_);
  k_gather<<<(N_ + 3) / 4, 256, 0, stream>>>(head, pay, xp, out, N_, E_);
}